// Round 8
// baseline (256.865 us; speedup 1.0000x reference)
//
#include <hip/hip_runtime.h>
#include <math.h>

#define VOCAB  100000
#define DIM    300
#define IDIM   320         // padded int8 row: 320 B
#define BB     4096
#define LL     200
#define HIDDEN 1000
#define OUTC   3
#define KT     19          // ceil(600/32) k-tiles of 32
#define NT     64          // n-tiles of 16, padded 1000 -> 1024
#define MTILES (BB / 16)   // 256 m-tiles of 16 rows

#define QSCALE (6.0f / 127.0f)
#define QINV   (127.0f / 6.0f)

#define W1_BLKS   ((KT * NT * 64 + 255) / 256)     // 304
#define INIT_BLKS ((BB * OUTC + 255) / 256)        // 48
#define CONV_BLKS ((VOCAB * 20 + 255) / 256)       // 7813

typedef __attribute__((ext_vector_type(8))) short  short8;
typedef __attribute__((ext_vector_type(4))) float  floatx4;
typedef __attribute__((ext_vector_type(2))) unsigned short ushort2v;

__device__ inline ushort f2bf(float f) {            // RNE float -> bf16 bits
    union { float f; unsigned u; } v; v.f = f;
    unsigned u = v.u;
    u += 0x7fffu + ((u >> 16) & 1u);
    return (ushort)(u >> 16);
}
__device__ inline float4 f4max(float4 a, float4 b) {
    return make_float4(fmaxf(a.x, b.x), fmaxf(a.y, b.y), fmaxf(a.z, b.z), fmaxf(a.w, b.w));
}
__device__ inline float4 f4add(float4 a, float4 b) {
    return make_float4(a.x + b.x, a.y + b.y, a.z + b.z, a.w + b.w);
}
__device__ inline unsigned pkmax16(unsigned a, unsigned b) {  // packed u16 max
    union { unsigned u; ushort2v v; } x, y, r;
    x.u = a; y.u = b;
    r.v = __builtin_elementwise_max(x.v, y.v);
    return r.u;
}

// slot (in ushorts) of element k, row-in-tile ml, in blocked A [kt][64][8]
__device__ inline int a_slot(int k, int ml) {
    const int kt = k >> 5, kk = k & 31;
    return ((kt << 6) + ml + ((kk >> 3) << 4)) * 8 + (kk & 7);
}

__device__ inline unsigned q4(float a, float b, float c, float d) {
    int q0 = min(max(__float2int_rn(a * QINV) + 128, 0), 255);
    int q1 = min(max(__float2int_rn(b * QINV) + 128, 0), 255);
    int q2 = min(max(__float2int_rn(c * QINV) + 128, 0), 255);
    int q3 = min(max(__float2int_rn(d * QINV) + 128, 0), 255);
    return (unsigned)q0 | ((unsigned)q1 << 8) | ((unsigned)q2 << 16) | ((unsigned)q3 << 24);
}

// SWAR accumulate helpers: word w holds dims {4w..4w+3} as 4 u8 codes.
__device__ inline void acc_sm(const uint4& raw, unsigned* sLo, unsigned* sHi,
                              unsigned* mLo, unsigned* mHi) {
    const unsigned* ww = (const unsigned*)&raw;
    #pragma unroll
    for (int w = 0; w < 4; ++w) {
        const unsigned u  = ww[w];
        const unsigned lo = u & 0x00FF00FFu;
        const unsigned hi = (u >> 8) & 0x00FF00FFu;
        sLo[w] += lo;  sHi[w] += hi;
        mLo[w] = pkmax16(mLo[w], lo);
        mHi[w] = pkmax16(mHi[w], hi);
    }
}
__device__ inline void acc_s(const uint4& raw, unsigned* sLo, unsigned* sHi) {
    const unsigned* ww = (const unsigned*)&raw;
    #pragma unroll
    for (int w = 0; w < 4; ++w) {
        const unsigned u = ww[w];
        sLo[w] += u & 0x00FF00FFu;
        sHi[w] += (u >> 8) & 0x00FF00FFu;
    }
}

// ---------------------------------------------------------------------------
// prep_all: [0,W1_BLKS) pack W1 -> bf16 B-frag; [..+INIT_BLKS) out=b2;
// [..+CONV_BLKS) quantize emb -> uint8[100000][320]  (only if doConv).
// ---------------------------------------------------------------------------
__global__ __launch_bounds__(256) void prep_all(
    const float* __restrict__ emb, unsigned char* __restrict__ embQ,
    const float* __restrict__ W1,  ushort* __restrict__ w1p,
    const float* __restrict__ b2,  float* __restrict__ out)
{
    const int bid = blockIdx.x;
    const int tid = threadIdx.x;
    if (bid < W1_BLKS) {
        const int g = bid * 256 + tid;                 // (kt*NT + nt)*64 + lane
        if (g >= KT * NT * 64) return;
        const int lane = g & 63;
        const int nt   = (g >> 6) & (NT - 1);
        const int kt   = g >> 12;
        const int n    = nt * 16 + (lane & 15);
        const int kb   = kt * 32 + ((lane >> 4) << 3);
        short8 v;
        #pragma unroll
        for (int j = 0; j < 8; ++j) {
            const int k = kb + j;
            const float f = (k < 600 && n < HIDDEN) ? W1[k * HIDDEN + n] : 0.f;
            v[j] = (short)f2bf(f);
        }
        ((short8*)w1p)[g] = v;
    } else if (bid < W1_BLKS + INIT_BLKS) {
        const int g = (bid - W1_BLKS) * 256 + tid;
        if (g < BB * OUTC) out[g] = b2[g % OUTC];
    } else {
        const int g = (bid - W1_BLKS - INIT_BLKS) * 256 + tid;   // row*20 + c
        if (g >= VOCAB * 20) return;
        const int row = g / 20;
        const int c   = g - row * 20;
        const float4* rp = (const float4*)(emb + (size_t)row * DIM);
        uint4 o;
        unsigned* ow = (unsigned*)&o;
        #pragma unroll
        for (int v = 0; v < 4; ++v) {
            const int fi = 4 * c + v;
            float4 f = (fi < 75) ? rp[fi] : make_float4(0.f, 0.f, 0.f, 0.f);
            ow[v] = q4(f.x, f.y, f.z, f.w);
        }
        *(uint4*)(embQ + (size_t)g * 16) = o;
    }
}

// ---------------------------------------------------------------------------
// int8 gather + pool, SWAR accumulate, pair-loop unrolled x2 (2 independent
// uint4 loads in flight per lane). 1 row/block, 4 waves = token quarters.
// Lanes 0..19 token A, 20..39 token B; lg covers dims 16lg..16lg+15.
// ---------------------------------------------------------------------------
__global__ __launch_bounds__(256, 8) void gather_pool_i8(
    const unsigned char* __restrict__ embQ,
    const int*           __restrict__ x,
    const int*           __restrict__ lengths,
    ushort*              __restrict__ repA)
{
    __shared__ int      xS[LL];
    __shared__ unsigned pS[3][20][8];
    __shared__ unsigned pM[3][20][8];

    const int tid  = threadIdx.x;
    const int lane = tid & 63;
    const int wave = tid >> 6;
    const int row  = blockIdx.x;

    for (int i = tid; i < LL; i += 256) xS[i] = x[row * LL + i];
    const int len = lengths[row];                 // >= 1
    __syncthreads();

    const int  t0   = wave * 50;
    const int  vmax = min(max(len - t0, 0), 50);
    const bool ga   = (lane < 20);
    const bool ld   = (lane < 40);
    const int  lg   = ga ? lane : (lane - 20);
    const unsigned char* base = embQ + 16 * lg;

    unsigned sLo[4], sHi[4], mLo[4], mHi[4];
    #pragma unroll
    for (int w = 0; w < 4; ++w) { sLo[w] = sHi[w] = 0u; mLo[w] = mHi[w] = 0u; }
    // max init 0 safe: codes >= 0 and every row has >= 1 valid token.

    const int full = vmax >> 1;
    int p = 0;
    for (; p + 2 <= full; p += 2) {               // 4 tokens, 2 loads in flight
        const int tA = t0 + 2 * p;
        const int i0 = ga ? xS[tA]     : xS[tA + 1];
        const int i1 = ga ? xS[tA + 2] : xS[tA + 3];
        uint4 r0 = make_uint4(0,0,0,0), r1 = make_uint4(0,0,0,0);
        if (ld) {
            r0 = *(const uint4*)(base + (size_t)i0 * IDIM);
            r1 = *(const uint4*)(base + (size_t)i1 * IDIM);
        }
        acc_sm(r0, sLo, sHi, mLo, mHi);
        acc_sm(r1, sLo, sHi, mLo, mHi);
    }
    if (p < full) {                               // leftover full pair
        const int tA = t0 + 2 * p;
        const int i0 = ga ? xS[tA] : xS[tA + 1];
        uint4 r0 = make_uint4(0,0,0,0);
        if (ld) r0 = *(const uint4*)(base + (size_t)i0 * IDIM);
        acc_sm(r0, sLo, sHi, mLo, mHi);
        ++p;
    }
    if (vmax & 1) {                               // A in max region, B sum-only
        const int tA = t0 + 2 * p;
        const int i0 = ga ? xS[tA] : xS[tA + 1];
        uint4 r0 = make_uint4(0,0,0,0);
        if (ld) r0 = *(const uint4*)(base + (size_t)i0 * IDIM);
        const unsigned* ww = (const unsigned*)&r0;
        #pragma unroll
        for (int w = 0; w < 4; ++w) {
            const unsigned u  = ww[w];
            const unsigned lo = u & 0x00FF00FFu;
            const unsigned hi = (u >> 8) & 0x00FF00FFu;
            sLo[w] += lo;  sHi[w] += hi;
            if (ga) { mLo[w] = pkmax16(mLo[w], lo); mHi[w] = pkmax16(mHi[w], hi); }
        }
        ++p;
    }
    for (; p + 2 <= 25; p += 2) {                 // sum-only, unrolled x2
        const int tA = t0 + 2 * p;
        const int i0 = ga ? xS[tA]     : xS[tA + 1];
        const int i1 = ga ? xS[tA + 2] : xS[tA + 3];
        uint4 r0 = make_uint4(0,0,0,0), r1 = make_uint4(0,0,0,0);
        if (ld) {
            r0 = *(const uint4*)(base + (size_t)i0 * IDIM);
            r1 = *(const uint4*)(base + (size_t)i1 * IDIM);
        }
        acc_s(r0, sLo, sHi);
        acc_s(r1, sLo, sHi);
    }
    if (p < 25) {
        const int tA = t0 + 2 * p;
        const int i0 = ga ? xS[tA] : xS[tA + 1];
        uint4 r0 = make_uint4(0,0,0,0);
        if (ld) r0 = *(const uint4*)(base + (size_t)i0 * IDIM);
        acc_s(r0, sLo, sHi);
    }

    // combine token-A / token-B lane groups
    {
        const int src = ga ? (lane + 20) : lane;
        #pragma unroll
        for (int w = 0; w < 4; ++w) {
            sLo[w] += (unsigned)__shfl((int)sLo[w], src);
            sHi[w] += (unsigned)__shfl((int)sHi[w], src);
            mLo[w] = pkmax16(mLo[w], (unsigned)__shfl((int)mLo[w], src));
            mHi[w] = pkmax16(mHi[w], (unsigned)__shfl((int)mHi[w], src));
        }
    }

    if (wave != 0 && ga) {
        #pragma unroll
        for (int w = 0; w < 4; ++w) {
            pS[wave - 1][lane][w]     = sLo[w];
            pS[wave - 1][lane][4 + w] = sHi[w];
            pM[wave - 1][lane][w]     = mLo[w];
            pM[wave - 1][lane][4 + w] = mHi[w];
        }
    }
    __syncthreads();
    if (wave == 0 && ga) {
        #pragma unroll
        for (int wv = 0; wv < 3; ++wv)
            #pragma unroll
            for (int w = 0; w < 4; ++w) {
                sLo[w] += pS[wv][lane][w];
                sHi[w] += pS[wv][lane][4 + w];
                mLo[w] = pkmax16(mLo[w], pM[wv][lane][w]);
                mHi[w] = pkmax16(mHi[w], pM[wv][lane][4 + w]);
            }

        float s[16], m[16];
        #pragma unroll
        for (int w = 0; w < 4; ++w) {
            s[4*w+0] = (float)(sLo[w] & 0xFFFFu);
            s[4*w+2] = (float)(sLo[w] >> 16);
            s[4*w+1] = (float)(sHi[w] & 0xFFFFu);
            s[4*w+3] = (float)(sHi[w] >> 16);
            m[4*w+0] = (float)(mLo[w] & 0xFFFFu);
            m[4*w+2] = (float)(mLo[w] >> 16);
            m[4*w+1] = (float)(mHi[w] & 0xFFFFu);
            m[4*w+3] = (float)(mHi[w] >> 16);
        }

        const float c1 = QSCALE / (float)len;     // mean=(S-128*200)*QSCALE/len
        const int mt = row >> 4;
        const int ml = row & 15;
        ushort* rb = repA + (size_t)mt * (KT * 512);

        ushort mv[16];
        #pragma unroll
        for (int j = 0; j < 16; ++j) mv[j] = f2bf((m[j] - 128.f) * QSCALE);

        if (lane < 18) {
            #pragma unroll
            for (int h = 0; h < 2; ++h) {
                short8 q;
                #pragma unroll
                for (int j = 0; j < 8; ++j)
                    q[j] = (short)f2bf((s[8*h + j] - 25600.f) * c1);
                *(short8*)(rb + a_slot(16 * lane + 8 * h, ml)) = q;
            }
            #pragma unroll
            for (int h = 0; h < 2; ++h) {
                const int k0 = 300 + 16 * lane + 8 * h;
                *(ushort4*)(rb + a_slot(k0, ml)) =
                    make_ushort4(mv[8*h+0], mv[8*h+1], mv[8*h+2], mv[8*h+3]);
                *(ushort4*)(rb + a_slot(k0 + 4, ml)) =
                    make_ushort4(mv[8*h+4], mv[8*h+5], mv[8*h+6], mv[8*h+7]);
            }
        } else if (lane == 18) {
            short8 q;
            #pragma unroll
            for (int j = 0; j < 8; ++j) q[j] = (short)f2bf((s[j] - 25600.f) * c1);
            *(short8*)(rb + a_slot(288, ml)) = q;
            *(ushort4*)(rb + a_slot(296, ml)) =
                make_ushort4(f2bf((s[8] - 25600.f) * c1), f2bf((s[9] - 25600.f) * c1),
                             f2bf((s[10] - 25600.f) * c1), f2bf((s[11] - 25600.f) * c1));
            *(ushort4*)(rb + a_slot(588, ml)) = make_ushort4(mv[0], mv[1], mv[2], mv[3]);
            *(ushort4*)(rb + a_slot(592, ml)) = make_ushort4(mv[4], mv[5], mv[6], mv[7]);
            *(ushort4*)(rb + a_slot(596, ml)) = make_ushort4(mv[8], mv[9], mv[10], mv[11]);
            *(ushort4*)(rb + a_slot(600, ml)) = make_ushort4(0, 0, 0, 0);
        } else {
            *(ushort4*)(rb + a_slot(604, ml)) = make_ushort4(0, 0, 0, 0);
        }
    }
}

// ---------------------------------------------------------------------------
// fp32 fallback gather (used only if ws too small for embQ).
// ---------------------------------------------------------------------------
__global__ __launch_bounds__(256, 8) void gather_pool_f32(
    const float* __restrict__ emb,
    const int*   __restrict__ x,
    const int*   __restrict__ lengths,
    ushort*      __restrict__ repA)
{
    __shared__ int    xS[LL];
    __shared__ float4 pS[3][75];
    __shared__ float4 pM[3][75];

    const int tid  = threadIdx.x;
    const int lane = tid & 63;
    const int wave = tid >> 6;
    const int row  = blockIdx.x;

    for (int i = tid; i < LL; i += 256) xS[i] = x[row * LL + i];
    const int len = lengths[row];
    __syncthreads();

    const int  t0   = wave * (LL / 4);
    const int  vmax = min(max(len - t0, 0), LL / 4);
    const bool tl   = (lane < 11);
    const float4 z4 = make_float4(0.f, 0.f, 0.f, 0.f);

    float4 s4 = z4, st = z4;
    float4 m4 = make_float4(-INFINITY, -INFINITY, -INFINITY, -INFINITY);
    float4 mt = m4;

    int t = 0;
    #pragma unroll 4
    for (; t < vmax; ++t) {
        const int idx = xS[t0 + t];
        const float4* rp = (const float4*)(emb + (size_t)idx * DIM);
        float4 a = rp[lane];
        float4 b = tl ? rp[64 + lane] : z4;
        s4 = f4add(s4, a); st = f4add(st, b);
        m4 = f4max(m4, a); mt = f4max(mt, b);
    }
    #pragma unroll 4
    for (; t < LL / 4; ++t) {
        const int idx = xS[t0 + t];
        const float4* rp = (const float4*)(emb + (size_t)idx * DIM);
        float4 a = rp[lane];
        float4 b = tl ? rp[64 + lane] : z4;
        s4 = f4add(s4, a); st = f4add(st, b);
    }

    if (wave != 0) {
        pS[wave - 1][lane] = s4; pM[wave - 1][lane] = m4;
        if (tl) { pS[wave - 1][64 + lane] = st; pM[wave - 1][64 + lane] = mt; }
    }
    __syncthreads();
    if (wave == 0) {
        #pragma unroll
        for (int w = 0; w < 3; ++w) {
            s4 = f4add(s4, pS[w][lane]); m4 = f4max(m4, pM[w][lane]);
            if (tl) { st = f4add(st, pS[w][64 + lane]); mt = f4max(mt, pM[w][64 + lane]); }
        }
        const float inv = 1.0f / (float)len;
        const int mtile = row >> 4;
        const int ml    = row & 15;
        ushort* rb = repA + (size_t)mtile * (KT * 512);
        {
            ushort4 q = make_ushort4(f2bf(s4.x*inv), f2bf(s4.y*inv), f2bf(s4.z*inv), f2bf(s4.w*inv));
            *(ushort4*)(rb + a_slot(4 * lane, ml)) = q;
        }
        {
            ushort4 q = make_ushort4(f2bf(m4.x), f2bf(m4.y), f2bf(m4.z), f2bf(m4.w));
            *(ushort4*)(rb + a_slot(300 + 4 * lane, ml)) = q;
        }
        if (tl) {
            ushort4 q1 = make_ushort4(f2bf(st.x*inv), f2bf(st.y*inv), f2bf(st.z*inv), f2bf(st.w*inv));
            *(ushort4*)(rb + a_slot(256 + 4 * lane, ml)) = q1;
            ushort4 q2 = make_ushort4(f2bf(mt.x), f2bf(mt.y), f2bf(mt.z), f2bf(mt.w));
            *(ushort4*)(rb + a_slot(556 + 4 * lane, ml)) = q2;
        }
        if (lane >= 56) rb[a_slot(600 + (lane - 56), ml)] = 0;
    }
}

// ---------------------------------------------------------------------------
// MFMA MLP: block = (m-tile pair, n-eighth) -> 128 x 8 = 1024 blocks.
// Per kt each wave loads 2 A-frags (LDS) + 2 B-frags (global) and fires 4
// MFMAs (full cross reuse) -> B-traffic halves vs r7. red[] aliased into aS
// after a barrier to keep LDS at 38.9 KB (4 blocks/CU). Layer-2 fused;
// atomicAdd combine into out (pre-initialized to b2).
// ---------------------------------------------------------------------------
__global__ __launch_bounds__(256, 4) void mlp_mfma(
    const ushort* __restrict__ w1p,
    const ushort* __restrict__ repA,
    const float*  __restrict__ bias1,
    const float*  __restrict__ W2,
    float*        __restrict__ out)
{
    __shared__ short8 aS[2 * KT * 64];          // 38.9 KB, reused as red[]

    const int tid  = threadIdx.x;
    const int lane = tid & 63;
    const int wave = tid >> 6;
    const int mp   = blockIdx.x >> 3;           // m-tile pair 0..127
    const int e    = blockIdx.x & 7;            // n-eighth 0..7

    {   // stage A for m-tiles 2mp, 2mp+1 (contiguous in repA)
        const short8* ap = (const short8*)(repA + (size_t)(2 * mp) * (KT * 512));
        for (int i = tid; i < 2 * KT * 64; i += 256) aS[i] = ap[i];
    }
    __syncthreads();

    const int nt0 = e * 8 + wave;               // this wave's two n-tiles
    const int nt1 = nt0 + 4;
    const short8* bp = (const short8*)w1p;

    floatx4 acc[2][2];                          // [mi][s]
    #pragma unroll
    for (int mi = 0; mi < 2; ++mi)
        #pragma unroll
        for (int s = 0; s < 2; ++s) acc[mi][s] = (floatx4){0.f, 0.f, 0.f, 0.f};

    #pragma unroll
    for (int kt = 0; kt < KT; ++kt) {
        const short8 av0 = aS[kt * 64 + lane];
        const short8 av1 = aS[KT * 64 + kt * 64 + lane];
        const short8 bv0 = bp[(kt * NT + nt0) * 64 + lane];
        const short8 bv1 = bp[(kt * NT + nt1) * 64 + lane];
        acc[0][0] = __builtin_amdgcn_mfma_f32_16x16x32_bf16(av0, bv0, acc[0][0], 0, 0, 0);
        acc[0][1] = __builtin_amdgcn_mfma_f32_16x16x32_bf16(av0, bv1, acc[0][1], 0, 0, 0);
        acc[1][0] = __builtin_amdgcn_mfma_f32_16x16x32_bf16(av1, bv0, acc[1][0], 0, 0, 0);
        acc[1][1] = __builtin_amdgcn_mfma_f32_16x16x32_bf16(av1, bv1, acc[1][1], 0, 0, 0);
    }
    __syncthreads();                            // aS reads done -> alias red
    float* red = (float*)aS;                    // [4][32][3] = 384 floats

    float po[2][4][3];
    #pragma unroll
    for (int mi = 0; mi < 2; ++mi)
        #pragma unroll
        for (int rg = 0; rg < 4; ++rg)
            #pragma unroll
            for (int j = 0; j < OUTC; ++j) po[mi][rg][j] = 0.f;

    #pragma unroll
    for (int s = 0; s < 2; ++s) {
        const int n = (s ? nt1 : nt0) * 16 + (lane & 15);
        const bool valid = (n < HIDDEN);
        const float bb  = bias1[valid ? n : 0];
        const float w20 = valid ? W2[n * 3 + 0] : 0.f;
        const float w21 = valid ? W2[n * 3 + 1] : 0.f;
        const float w22 = valid ? W2[n * 3 + 2] : 0.f;
        #pragma unroll
        for (int mi = 0; mi < 2; ++mi)
            #pragma unroll
            for (int rg = 0; rg < 4; ++rg) {
                const float h = fmaxf(acc[mi][s][rg] + bb, 0.f);
                po[mi][rg][0] = fmaf(h, w20, po[mi][rg][0]);
                po[mi][rg][1] = fmaf(h, w21, po[mi][rg][1]);
                po[mi][rg][2] = fmaf(h, w22, po[mi][rg][2]);
            }
    }

    #pragma unroll
    for (int mi = 0; mi < 2; ++mi)
        #pragma unroll
        for (int rg = 0; rg < 4; ++rg)
            #pragma unroll
            for (int j = 0; j < OUTC; ++j) {
                float v = po[mi][rg][j];
                v += __shfl_xor(v, 1);
                v += __shfl_xor(v, 2);
                v += __shfl_xor(v, 4);
                v += __shfl_xor(v, 8);
                if ((lane & 15) == 0)
                    red[(wave * 32 + mi * 16 + (lane >> 4) * 4 + rg) * 3 + j] = v;
            }
    __syncthreads();

    if (tid < 32 * OUTC) {
        const int m = tid / OUTC, j = tid % OUTC;
        const float s = red[(0 * 32 + m) * 3 + j] + red[(1 * 32 + m) * 3 + j]
                      + red[(2 * 32 + m) * 3 + j] + red[(3 * 32 + m) * 3 + j];
        atomicAdd(&out[(size_t)(mp * 32 + m) * OUTC + j], s);
    }
}

extern "C" void kernel_launch(void* const* d_in, const int* in_sizes, int n_in,
                              void* d_out, int out_size, void* d_ws, size_t ws_size,
                              hipStream_t stream) {
    const float* emb = (const float*)d_in[0];
    const float* W1  = (const float*)d_in[1];
    const float* b1  = (const float*)d_in[2];
    const float* W2  = (const float*)d_in[3];
    const float* b2  = (const float*)d_in[4];
    const int*   x   = (const int*)d_in[5];
    const int*   len = (const int*)d_in[6];
    float* out = (float*)d_out;

    // ws layout: [w1p 1.245 MB][repA 4.981 MB][embQ 32.0 MB]
    const size_t W1P_ELTS  = (size_t)KT * NT * 64 * 8;          // ushorts
    const size_t REPA_ELTS = (size_t)MTILES * KT * 512;         // ushorts
    ushort* w1p  = (ushort*)d_ws;
    ushort* repA = w1p + W1P_ELTS;
    unsigned char* embQ = (unsigned char*)(repA + REPA_ELTS);
    const size_t need = (W1P_ELTS + REPA_ELTS) * 2 + (size_t)VOCAB * IDIM;
    const bool doConv = (ws_size >= need);

    const int prepGrid = W1_BLKS + INIT_BLKS + (doConv ? CONV_BLKS : 0);
    hipLaunchKernelGGL(prep_all, dim3(prepGrid), dim3(256), 0, stream,
                       emb, embQ, W1, w1p, b2, out);
    if (doConv) {
        hipLaunchKernelGGL(gather_pool_i8, dim3(BB), dim3(256), 0, stream,
                           embQ, x, len, repA);
    } else {
        hipLaunchKernelGGL(gather_pool_f32, dim3(BB), dim3(256), 0, stream,
                           emb, x, len, repA);
    }
    hipLaunchKernelGGL(mlp_mfma, dim3((MTILES / 2) * 8), dim3(256), 0, stream,
                       w1p, repA, b1, W2, out);
}